// Round 4
// baseline (105.794 us; speedup 1.0000x reference)
//
#include <hip/hip_runtime.h>
#include <hip/hip_bf16.h>

#define BATCH 128
#define NOUT  256
#define MB    8
#define IN    512

#define THREADS 256
#define TI 32            // i-tile per block (2 rows/thread)
#define TB 32            // b-tile per block (2 cols/thread)
#define CH 128           // k-chunk in floats
#define CH4 (CH/4)       // 32 float4 per row-chunk
#define PLANE (BATCH*NOUT)

__device__ __forceinline__ float fast_exp2(float v) {
#if __has_builtin(__builtin_amdgcn_exp2f)
  return __builtin_amdgcn_exp2f(v);
#else
  return exp2f(v);
#endif
}
__device__ __forceinline__ float fast_rcp(float v) {
#if __has_builtin(__builtin_amdgcn_rcpf)
  return __builtin_amdgcn_rcpf(v);
#else
  return 1.0f / v;
#endif
}

// sum of 4 sigmoids from pre-scaled products p_i = -log2e * x*w, one rcp:
// e_i = 2^{p_i} = e^{-v_i}; sigma(v)=1/(1+e); sum = ((A+B)*CD + (C+D)*AB)/(AB*CD)
__device__ __forceinline__ float sig4(float4 p) {
  float ea = fast_exp2(p.x), eb = fast_exp2(p.y), ec = fast_exp2(p.z), ed = fast_exp2(p.w);
  float A = 1.0f + ea, B = 1.0f + eb, C = 1.0f + ec, D = 1.0f + ed;
  float AB = A * B, CD = C * D;
  float num = fmaf(A + B, CD, (C + D) * AB);
  return num * fast_rcp(AB * CD);
}
__device__ __forceinline__ float4 mul4(float4 a, float4 b) {
  return make_float4(a.x * b.x, a.y * b.y, a.z * b.z, a.w * b.w);
}

// Kernel A: part[z][i][b] = prod_{j in range} sum_{k in chunk range} sigmoid(x*w)
// XOR-swizzled LDS: float4 col c4 of row r stored at c4 ^ ((r>>1)&7).
// Read conflicts: x rows (4 distinct/wave) conflict-free; w rows (16 distinct/wave)
// spread over 8 start-banks -> 2-way = free (m136). Write side: permutation per row.
template<int JPB, int KCB>
__global__ __launch_bounds__(THREADS, 4) void dnm_partial_kernel(
    const float* __restrict__ x, const float* __restrict__ w,
    float* __restrict__ part)
{
  __shared__ float4 xs4[TI * 32];
  __shared__ float4 ws4[TB * 32];

  const int t   = threadIdx.x;
  const int ti2 = t >> 4;     // 0..15 -> i rows i0+2*ti2, +1
  const int tb2 = t & 15;     // 0..15 -> b cols b0+2*tb2, +1
  const int b0  = blockIdx.x * TB;
  const int i0  = blockIdx.y * TI;
  constexpr int KG = (IN / CH) / KCB;          // k-groups across blocks (compile-time)
  const int j0  = (blockIdx.z / KG) * JPB;
  const int q0  = (blockIdx.z % KG) * KCB;

  const float4* gx = (const float4*)x;
  const float4* gw = (const float4*)w;
  const float NEG_LOG2E = -1.4426950408889634f;

  float p00 = 1.0f, p01 = 1.0f, p10 = 1.0f, p11 = 1.0f;
  #pragma unroll
  for (int jj = 0; jj < JPB; ++jj) {
    const int j = j0 + jj;
    float s00 = 0.0f, s01 = 0.0f, s10 = 0.0f, s11 = 0.0f;
    #pragma unroll
    for (int cc = 0; cc < KCB; ++cc) {
      const int q = q0 + cc;
      __syncthreads();
      #pragma unroll
      for (int p = 0; p < (2 * TI * CH4) / THREADS; ++p) {
        int idx = t + p * THREADS;
        int r = idx >> 5, c4 = idx & 31;
        int c4s = c4 ^ ((r >> 1) & 7);         // XOR swizzle
        if (r < TI) {
          float4 xv = gx[(size_t)((i0 + r) * MB + j) * (IN / 4) + q * CH4 + c4];
          xv.x *= NEG_LOG2E; xv.y *= NEG_LOG2E; xv.z *= NEG_LOG2E; xv.w *= NEG_LOG2E;
          xs4[r * 32 + c4s] = xv;
        } else {
          ws4[(r - TI) * 32 + c4s] =
              gw[(size_t)((b0 + r - TI) * MB + j) * (IN / 4) + q * CH4 + c4];
        }
      }
      __syncthreads();
      const int sx = ti2 & 7, sw = tb2 & 7;
      const float4* __restrict__ xb0 = &xs4[(2 * ti2) * 32];
      const float4* __restrict__ wb0 = &ws4[(2 * tb2) * 32];
      #pragma unroll 4
      for (int k4 = 0; k4 < CH4; ++k4) {
        int kx = k4 ^ sx, kw = k4 ^ sw;
        float4 xv0 = xb0[kx], xv1 = xb0[32 + kx];
        float4 wv0 = wb0[kw], wv1 = wb0[32 + kw];
        s00 += sig4(mul4(xv0, wv0));
        s01 += sig4(mul4(xv0, wv1));
        s10 += sig4(mul4(xv1, wv0));
        s11 += sig4(mul4(xv1, wv1));
      }
    }
    p00 *= s00; p01 *= s01; p10 *= s10; p11 *= s11;
  }
  float* dst = part + (size_t)blockIdx.z * PLANE;
  const int i = i0 + 2 * ti2, b = b0 + 2 * tb2;
  dst[(size_t)i * NOUT + b]           = p00;
  dst[(size_t)i * NOUT + b + 1]       = p01;
  dst[(size_t)(i + 1) * NOUT + b]     = p10;
  dst[(size_t)(i + 1) * NOUT + b + 1] = p11;
}

__device__ __forceinline__ float block_sum(float v, float* red) {
  #pragma unroll
  for (int o = 32; o > 0; o >>= 1) v += __shfl_down(v, o, 64);
  int lane = threadIdx.x & 63, wid = threadIdx.x >> 6;
  __syncthreads();
  if (lane == 0) red[wid] = v;
  __syncthreads();
  return red[0] + red[1] + red[2] + red[3];
}

// Kernel B (templated -> fully unrolled, pipelined plane loads):
// z[i][b] = prod_j sum_q part[j*KG+q][i][b]; then row-normalize + standardize (ddof=1)
template<int JG, int KG>
__global__ __launch_bounds__(256) void dnm_norm_kernel(
    const float* __restrict__ part, float* __restrict__ out)
{
  __shared__ float red[4];
  const int i = blockIdx.x;
  const int t = threadIdx.x;
  float z = 1.0f;
  #pragma unroll
  for (int j = 0; j < JG; ++j) {
    float s = 0.0f;
    #pragma unroll
    for (int q = 0; q < KG; ++q)
      s += part[(size_t)(j * KG + q) * PLANE + (size_t)i * NOUT + t];
    z *= s;
  }
  float S  = block_sum(z, red);
  float zn = z / S;
  float m  = block_sum(zn, red) * (1.0f / NOUT);
  float dv = zn - m;
  float v  = block_sum(dv * dv, red) * (1.0f / (NOUT - 1));
  out[(size_t)i * NOUT + t] = dv / sqrtf(v);
}

extern "C" void kernel_launch(void* const* d_in, const int* in_sizes, int n_in,
                              void* d_out, int out_size, void* d_ws, size_t ws_size,
                              hipStream_t stream) {
  const float* x = (const float*)d_in[0];   // (128, 8, 512)
  const float* w = (const float*)d_in[1];   // (256, 8, 512)
  float* out = (float*)d_out;               // (128, 256)

  const size_t plane_bytes = (size_t)PLANE * sizeof(float);

  if (ws_size >= 64 * plane_bytes) {
    // Main path. DIAGNOSTIC: kernel A launched twice (2nd into disjoint region,
    // result unread) to measure A's duration as dur(R4)-dur(R3). Same work every call.
    float* part  = (float*)d_ws;
    float* part2 = part + (size_t)32 * PLANE;
    dim3 gridA(NOUT / TB, BATCH / TI, 32);   // jg=8 x kg=4
    dnm_partial_kernel<1, 1><<<gridA, THREADS, 0, stream>>>(x, w, part);
    dnm_partial_kernel<1, 1><<<gridA, THREADS, 0, stream>>>(x, w, part2);
    dnm_norm_kernel<8, 4><<<dim3(BATCH), 256, 0, stream>>>(part, out);
  } else if (ws_size >= 32 * plane_bytes) {
    float* part = (float*)d_ws;
    dim3 gridA(NOUT / TB, BATCH / TI, 32);
    dnm_partial_kernel<1, 1><<<gridA, THREADS, 0, stream>>>(x, w, part);
    dnm_norm_kernel<8, 4><<<dim3(BATCH), 256, 0, stream>>>(part, out);
  } else if (ws_size >= plane_bytes) {
    float* part = (float*)d_ws;
    dim3 gridA(NOUT / TB, BATCH / TI, 1);    // one block-z does all j,k
    dnm_partial_kernel<8, 4><<<gridA, THREADS, 0, stream>>>(x, w, part);
    dnm_norm_kernel<1, 1><<<dim3(BATCH), 256, 0, stream>>>(part, out);
  } else {
    float* part = out;                        // in-place fallback
    dim3 gridA(NOUT / TB, BATCH / TI, 1);
    dnm_partial_kernel<8, 4><<<gridA, THREADS, 0, stream>>>(x, w, part);
    dnm_norm_kernel<1, 1><<<dim3(BATCH), 256, 0, stream>>>(part, out);
  }
}

// Round 5
// 86.702 us; speedup vs baseline: 1.2202x; 1.2202x over previous
//
#include <hip/hip_runtime.h>
#include <hip/hip_bf16.h>

#define BATCH 128
#define NOUT  256
#define MB    8
#define IN    512

#define THREADS 256
#define TI 32            // i-tile per block (2 rows/thread)
#define TB 32            // b-tile per block (2 cols/thread)
#define CH 128           // k-chunk in floats
#define CH4 (CH/4)       // 32 float4 per row-chunk
#define PLANE (BATCH*NOUT)

typedef float v2f __attribute__((ext_vector_type(2)));

__device__ __forceinline__ float fast_exp2(float v) {
#if __has_builtin(__builtin_amdgcn_exp2f)
  return __builtin_amdgcn_exp2f(v);
#else
  return exp2f(v);
#endif
}
__device__ __forceinline__ float fast_rcp(float v) {
#if __has_builtin(__builtin_amdgcn_rcpf)
  return __builtin_amdgcn_rcpf(v);
#else
  return 1.0f / v;
#endif
}

// Sum of 4 sigmoids with ONE rcp, formulated for packed-FP32 (v_pk_*) emission.
// Inputs p_i = -log2e * x*w  (x pre-scaled); e_i = 2^{p_i} = e^{-v_i}; A_i = 1+e_i.
// sum 1/A_i = ((A+B)*CD + (C+D)*AB) / (AB*CD), pairs arranged as [A,C],[B,D].
__device__ __forceinline__ float sig4(v2f p02, v2f p13) {
  float e0 = fast_exp2(p02.x), e2 = fast_exp2(p02.y);
  float e1 = fast_exp2(p13.x), e3 = fast_exp2(p13.y);
  v2f f02 = {e0, e2}; f02 += 1.0f;          // [A, C]   v_pk_add
  v2f f13 = {e1, e3}; f13 += 1.0f;          // [B, D]   v_pk_add
  v2f prod = f02 * f13;                      // [AB, CD] v_pk_mul
  v2f sum  = f02 + f13;                      // [A+B, C+D] v_pk_add
  v2f prodsw = __builtin_shufflevector(prod, prod, 1, 0);  // [CD, AB] (op_sel)
  v2f t = sum * prodsw;                      // [(A+B)CD, (C+D)AB] v_pk_mul
  float num = t.x + t.y;
  float den = prod.x * prod.y;
  return num * fast_rcp(den);
}

// Kernel A: part[z][i][b] = prod_{j range} sum_{k chunk range} sigmoid(x*w)
// Main path JPB=1,KCB=1: 1024 blocks (4/CU), one staging phase, 2 barriers.
// XOR-swizzled LDS (c4 ^ (row>>1)&7): w-row reads 8 start-banks -> 2-way = free.
template<int JPB, int KCB>
__global__ __launch_bounds__(THREADS, 4) void dnm_partial_kernel(
    const float* __restrict__ x, const float* __restrict__ w,
    float* __restrict__ part)
{
  __shared__ float4 xs4[TI * 32];
  __shared__ float4 ws4[TB * 32];

  const int t   = threadIdx.x;
  const int ti2 = t >> 4;     // 0..15 -> i rows i0+2*ti2, +1
  const int tb2 = t & 15;     // 0..15 -> b cols b0+2*tb2, +1
  const int b0  = blockIdx.x * TB;
  const int i0  = blockIdx.y * TI;
  constexpr int KG = (IN / CH) / KCB;
  const int j0  = (blockIdx.z / KG) * JPB;
  const int q0  = (blockIdx.z % KG) * KCB;

  const float4* gx = (const float4*)x;
  const float4* gw = (const float4*)w;
  const float NEG_LOG2E = -1.4426950408889634f;

  float p00 = 1.0f, p01 = 1.0f, p10 = 1.0f, p11 = 1.0f;
  #pragma unroll
  for (int jj = 0; jj < JPB; ++jj) {
    const int j = j0 + jj;
    float s00 = 0.0f, s01 = 0.0f, s10 = 0.0f, s11 = 0.0f;
    #pragma unroll
    for (int cc = 0; cc < KCB; ++cc) {
      const int q = q0 + cc;
      __syncthreads();
      #pragma unroll
      for (int p = 0; p < (2 * TI * CH4) / THREADS; ++p) {
        int idx = t + p * THREADS;
        int r = idx >> 5, c4 = idx & 31;
        int c4s = c4 ^ ((r >> 1) & 7);
        if (r < TI) {
          float4 xv = gx[(size_t)((i0 + r) * MB + j) * (IN / 4) + q * CH4 + c4];
          xv.x *= NEG_LOG2E; xv.y *= NEG_LOG2E; xv.z *= NEG_LOG2E; xv.w *= NEG_LOG2E;
          xs4[r * 32 + c4s] = xv;
        } else {
          ws4[(r - TI) * 32 + c4s] =
              gw[(size_t)((b0 + r - TI) * MB + j) * (IN / 4) + q * CH4 + c4];
        }
      }
      __syncthreads();
      const int sx = ti2 & 7, sw = tb2 & 7;
      const float4* __restrict__ xb0 = &xs4[(2 * ti2) * 32];
      const float4* __restrict__ wb0 = &ws4[(2 * tb2) * 32];
      #pragma unroll 4
      for (int k4 = 0; k4 < CH4; ++k4) {
        int kx = k4 ^ sx, kw = k4 ^ sw;
        float4 xv0 = xb0[kx], xv1 = xb0[32 + kx];
        float4 wv0 = wb0[kw], wv1 = wb0[32 + kw];
        // split each float4 into [e0,e2]/[e1,e3] pair layout for pk math
        v2f x0a = {xv0.x, xv0.z}, x0b = {xv0.y, xv0.w};
        v2f x1a = {xv1.x, xv1.z}, x1b = {xv1.y, xv1.w};
        v2f w0a = {wv0.x, wv0.z}, w0b = {wv0.y, wv0.w};
        v2f w1a = {wv1.x, wv1.z}, w1b = {wv1.y, wv1.w};
        s00 += sig4(x0a * w0a, x0b * w0b);   // v_pk_mul products feed exp2
        s01 += sig4(x0a * w1a, x0b * w1b);
        s10 += sig4(x1a * w0a, x1b * w0b);
        s11 += sig4(x1a * w1a, x1b * w1b);
      }
    }
    p00 *= s00; p01 *= s01; p10 *= s10; p11 *= s11;
  }
  float* dst = part + (size_t)blockIdx.z * PLANE;
  const int i = i0 + 2 * ti2, b = b0 + 2 * tb2;
  dst[(size_t)i * NOUT + b]           = p00;
  dst[(size_t)i * NOUT + b + 1]       = p01;
  dst[(size_t)(i + 1) * NOUT + b]     = p10;
  dst[(size_t)(i + 1) * NOUT + b + 1] = p11;
}

__device__ __forceinline__ float block_sum(float v, float* red) {
  #pragma unroll
  for (int o = 32; o > 0; o >>= 1) v += __shfl_down(v, o, 64);
  int lane = threadIdx.x & 63, wid = threadIdx.x >> 6;
  __syncthreads();
  if (lane == 0) red[wid] = v;
  __syncthreads();
  return red[0] + red[1] + red[2] + red[3];
}

// Kernel B: z[i][b] = prod_j sum_q part[j*KG+q][i][b]; row-normalize + standardize (ddof=1)
template<int JG, int KG>
__global__ __launch_bounds__(256) void dnm_norm_kernel(
    const float* __restrict__ part, float* __restrict__ out)
{
  __shared__ float red[4];
  const int i = blockIdx.x;
  const int t = threadIdx.x;
  float z = 1.0f;
  #pragma unroll
  for (int j = 0; j < JG; ++j) {
    float s = 0.0f;
    #pragma unroll
    for (int q = 0; q < KG; ++q)
      s += part[(size_t)(j * KG + q) * PLANE + (size_t)i * NOUT + t];
    z *= s;
  }
  float S  = block_sum(z, red);
  float zn = z / S;
  float m  = block_sum(zn, red) * (1.0f / NOUT);
  float dv = zn - m;
  float v  = block_sum(dv * dv, red) * (1.0f / (NOUT - 1));
  out[(size_t)i * NOUT + t] = dv / sqrtf(v);
}

extern "C" void kernel_launch(void* const* d_in, const int* in_sizes, int n_in,
                              void* d_out, int out_size, void* d_ws, size_t ws_size,
                              hipStream_t stream) {
  const float* x = (const float*)d_in[0];   // (128, 8, 512)
  const float* w = (const float*)d_in[1];   // (256, 8, 512)
  float* out = (float*)d_out;               // (128, 256)

  const size_t plane_bytes = (size_t)PLANE * sizeof(float);

  if (ws_size >= 32 * plane_bytes) {
    // Main path: jg=8 x kg=4 -> 1024 blocks, 4/CU.
    float* part = (float*)d_ws;
    dim3 gridA(NOUT / TB, BATCH / TI, 32);
    dnm_partial_kernel<1, 1><<<gridA, THREADS, 0, stream>>>(x, w, part);
    dnm_norm_kernel<8, 4><<<dim3(BATCH), 256, 0, stream>>>(part, out);
  } else if (ws_size >= plane_bytes) {
    float* part = (float*)d_ws;
    dim3 gridA(NOUT / TB, BATCH / TI, 1);
    dnm_partial_kernel<8, 4><<<gridA, THREADS, 0, stream>>>(x, w, part);
    dnm_norm_kernel<1, 1><<<dim3(BATCH), 256, 0, stream>>>(part, out);
  } else {
    float* part = out;                        // in-place fallback
    dim3 gridA(NOUT / TB, BATCH / TI, 1);
    dnm_partial_kernel<8, 4><<<gridA, THREADS, 0, stream>>>(x, w, part);
    dnm_norm_kernel<1, 1><<<dim3(BATCH), 256, 0, stream>>>(part, out);
  }
}